// Round 1
// baseline (4688.186 us; speedup 1.0000x reference)
//
#include <hip/hip_runtime.h>

typedef __attribute__((ext_vector_type(4))) float f32x4;
typedef __attribute__((ext_vector_type(2))) float f32x2;
typedef __attribute__((ext_vector_type(8))) short s16x8;
typedef __attribute__((ext_vector_type(4))) short s16x4;

#define B_ 64
#define S_ 128
#define T_ 32
#define H_ 512
#define V_ 32000

__device__ __forceinline__ unsigned short f2bf(float f) {
  union { float f; unsigned u; } x; x.f = f;
  unsigned r = x.u + 0x7FFFu + ((x.u >> 16) & 1u);
  return (unsigned short)(r >> 16);
}

__device__ __forceinline__ float fast_tanh(float x) {
  float e = __expf(2.0f * x);
  return 1.0f - 2.0f / (e + 1.0f);
}
__device__ __forceinline__ float fast_sig(float x) {
  return 1.0f / (1.0f + __expf(-x));
}

// ---------------------------------------------------------------------------
// Generic GEMM: C[M,N] = A[M,K] @ W[N,K]^T (+bias)
// A: f32 row-major (or encoder_out [S,B,2H] addressing when ENC=1, rows m=b*S+s)
// W: bf16 [N,K] row-major (WF32=1: f32, cast on the fly)
// grid = (N/64, M/64), block = 256 (4 waves), each wave does 16 rows x 64 cols.
// mfma_f32_16x16x32_bf16: A row=lane&15, k=(lane>>4)*8+j ; B col=lane&15 same k;
// C/D row=(lane>>4)*4+reg, col=lane&15  [per guide §3, m89/m91-verified]
// ---------------------------------------------------------------------------
template <int ENC, int WF32>
__global__ __launch_bounds__(256) void gemm_k(
    const float* __restrict__ A, const void* __restrict__ Wv,
    const float* __restrict__ bias, float* __restrict__ C, int N, int K) {
  __shared__ unsigned short As[64 * 32];
  __shared__ unsigned short Bs[64 * 32];
  const int t = threadIdx.x;
  const int wave = t >> 6, lane = t & 63;
  const int n0 = blockIdx.x * 64;
  const int m0 = blockIdx.y * 64;
  const int row = t >> 2, part = t & 3;

  const float* arow;
  if (ENC) {
    int m = m0 + row;  // m = b*S + s -> encoder_out[s][b][:]
    arow = A + ((size_t)(m & (S_ - 1)) * B_ + (m >> 7)) * (2 * H_);
  } else {
    arow = A + (size_t)(m0 + row) * K;
  }
  const char* wrow = (const char*)Wv + (size_t)(n0 + row) * K * (WF32 ? 4 : 2);

  f32x4 acc[4];
#pragma unroll
  for (int j = 0; j < 4; ++j) acc[j] = (f32x4){0.f, 0.f, 0.f, 0.f};

  const unsigned stg_off = (unsigned)(row * 64 + ((part ^ (row & 3)) << 4));
  const int ar = wave * 16 + (lane & 15);
  const unsigned a_off = (unsigned)(ar * 64 + (((lane >> 4) ^ (ar & 3)) << 4));

  for (int kk = 0; kk < K; kk += 32) {
    {  // stage A (f32 -> bf16)
      const float* p = arow + kk + part * 8;
      f32x4 f0 = *(const f32x4*)p;
      f32x4 f1 = *(const f32x4*)(p + 4);
      s16x8 vb;
#pragma unroll
      for (int j = 0; j < 4; ++j) {
        vb[j] = (short)f2bf(f0[j]);
        vb[4 + j] = (short)f2bf(f1[j]);
      }
      *(s16x8*)((char*)As + stg_off) = vb;
    }
    {  // stage B
      if (WF32) {
        const float* p = (const float*)wrow + kk + part * 8;
        f32x4 f0 = *(const f32x4*)p;
        f32x4 f1 = *(const f32x4*)(p + 4);
        s16x8 vb;
#pragma unroll
        for (int j = 0; j < 4; ++j) {
          vb[j] = (short)f2bf(f0[j]);
          vb[4 + j] = (short)f2bf(f1[j]);
        }
        *(s16x8*)((char*)Bs + stg_off) = vb;
      } else {
        const unsigned short* p = (const unsigned short*)wrow + kk + part * 8;
        *(s16x8*)((char*)Bs + stg_off) = *(const s16x8*)p;
      }
    }
    __syncthreads();
    s16x8 afrag = *(const s16x8*)((const char*)As + a_off);
#pragma unroll
    for (int j = 0; j < 4; ++j) {
      int cn = j * 16 + (lane & 15);
      s16x8 bfrag =
          *(const s16x8*)((const char*)Bs + cn * 64 + (((lane >> 4) ^ (cn & 3)) << 4));
      acc[j] = __builtin_amdgcn_mfma_f32_16x16x32_bf16(afrag, bfrag, acc[j], 0, 0, 0);
    }
    __syncthreads();
  }

#pragma unroll
  for (int j = 0; j < 4; ++j) {
    int col = n0 + j * 16 + (lane & 15);
    float bv = bias ? bias[col] : 0.0f;
#pragma unroll
    for (int i = 0; i < 4; ++i) {
      int r = m0 + wave * 16 + ((lane >> 4) << 2) + i;
      C[(size_t)r * N + col] = acc[j][i] + bv;
    }
  }
}

// ---------------------------------------------------------------------------
// Attention per step: scores = v . tanh(hproj + enc_proj), masked softmax,
// weighted = attn @ enc_bt, plus embedding gather. One block per batch b.
// ---------------------------------------------------------------------------
__global__ __launch_bounds__(256) void attn_k(
    const float* __restrict__ hgh, const float* __restrict__ enc_proj,
    const float* __restrict__ enc, const float* __restrict__ v,
    const int* __restrict__ src_tok, const int* __restrict__ trg_tok,
    const float* __restrict__ embed, int step, float* __restrict__ xw,
    float* __restrict__ out_feat) {
  const int b = blockIdx.x;
  const int t = threadIdx.x, wave = t >> 6, lane = t & 63;
  __shared__ float sc[S_];

  const float* hp = hgh + (size_t)b * 2048;  // hproj = cols 0..511
  float vh[8], hh[8];
  {
    f32x4 v0 = *(const f32x4*)(v + lane * 8);
    f32x4 v1 = *(const f32x4*)(v + lane * 8 + 4);
    f32x4 h0 = *(const f32x4*)(hp + lane * 8);
    f32x4 h1 = *(const f32x4*)(hp + lane * 8 + 4);
#pragma unroll
    for (int j = 0; j < 4; ++j) {
      vh[j] = v0[j]; vh[4 + j] = v1[j];
      hh[j] = h0[j]; hh[4 + j] = h1[j];
    }
  }
  for (int s = wave * 32; s < wave * 32 + 32; ++s) {
    const float* ep = enc_proj + ((size_t)b * S_ + s) * H_ + lane * 8;
    f32x4 e0 = *(const f32x4*)ep;
    f32x4 e1 = *(const f32x4*)(ep + 4);
    float p = 0.f;
#pragma unroll
    for (int j = 0; j < 4; ++j) p += vh[j] * fast_tanh(hh[j] + e0[j]);
#pragma unroll
    for (int j = 0; j < 4; ++j) p += vh[4 + j] * fast_tanh(hh[4 + j] + e1[j]);
    for (int m = 32; m; m >>= 1) p += __shfl_xor(p, m);
    if (lane == 0)
      sc[s] = (src_tok[b * S_ + s] != 0) ? p : -__builtin_inff();
  }
  __syncthreads();
  if (wave == 0) {
    float a0 = sc[lane], a1 = sc[lane + 64];
    float mx = fmaxf(a0, a1);
    for (int m = 32; m; m >>= 1) mx = fmaxf(mx, __shfl_xor(mx, m));
    float e0 = __expf(a0 - mx), e1 = __expf(a1 - mx);
    float ssum = e0 + e1;
    for (int m = 32; m; m >>= 1) ssum += __shfl_xor(ssum, m);
    float inv = 1.0f / ssum;
    sc[lane] = e0 * inv;
    sc[lane + 64] = e1 * inv;
  }
  __syncthreads();
  {  // weighted[b, d0..d0+3]
    const int d0 = t * 4;
    f32x4 acc = {0.f, 0.f, 0.f, 0.f};
    for (int s = 0; s < S_; ++s) {
      f32x4 e = *(const f32x4*)(enc + ((size_t)s * B_ + b) * (2 * H_) + d0);
      float a = sc[s];
#pragma unroll
      for (int j = 0; j < 4; ++j) acc[j] += a * e[j];
    }
    *(f32x4*)(xw + (size_t)b * 1536 + 512 + d0) = acc;
    *(f32x4*)(out_feat + (size_t)b * 2048 + 512 + d0) = acc;
  }
  {  // x = embed[tok] (PAD row -> 0)
    int tok = trg_tok[b * T_ + step];
    const int d0 = t * 2;
    f32x2 xv = {0.f, 0.f};
    if (tok != 0) xv = *(const f32x2*)(embed + (size_t)tok * H_ + d0);
    *(f32x2*)(xw + (size_t)b * 1536 + d0) = xv;
    *(f32x2*)(out_feat + (size_t)b * 2048 + 1536 + d0) = xv;
  }
}

// ---------------------------------------------------------------------------
// GRU elementwise: gates from gi (x,weighted @ W_ih^T) and gh (h @ W_hh^T)
// ---------------------------------------------------------------------------
__global__ __launch_bounds__(256) void gru_k(
    const float* __restrict__ gi, const float* __restrict__ hgh,
    const float* __restrict__ b_ih, const float* __restrict__ b_hh,
    const float* __restrict__ h_in, float* __restrict__ h_out,
    float* __restrict__ out_feat) {
  int i = blockIdx.x * 256 + threadIdx.x;  // 0..32767
  int b = i >> 9, d = i & 511;
  const float* gib = gi + (size_t)b * 1536;
  const float* gh = hgh + (size_t)b * 2048 + 512;  // gh = cols 512..2047
  float ir = gib[d] + b_ih[d];
  float iz = gib[512 + d] + b_ih[512 + d];
  float in_ = gib[1024 + d] + b_ih[1024 + d];
  float hr = gh[d] + b_hh[d];
  float hz = gh[512 + d] + b_hh[512 + d];
  float hn = gh[1024 + d] + b_hh[1024 + d];
  float r = fast_sig(ir + hr);
  float z = fast_sig(iz + hz);
  float n = fast_tanh(in_ + r * hn);
  float h = (1.0f - z) * n + z * h_in[(size_t)b * 512 + d];
  h_out[(size_t)b * 512 + d] = h;
  out_feat[(size_t)b * 2048 + d] = h;
}

// ---------------------------------------------------------------------------
// Weight prep kernels (once per launch)
// ---------------------------------------------------------------------------
__global__ __launch_bounds__(256) void cast_bf16_k(const float* __restrict__ src,
                                                   unsigned short* __restrict__ dst,
                                                   int n4) {
  int i = blockIdx.x * 256 + threadIdx.x;
  if (i >= n4) return;
  f32x4 f = *(const f32x4*)(src + (size_t)i * 4);
  s16x4 o;
#pragma unroll
  for (int j = 0; j < 4; ++j) o[j] = (short)f2bf(f[j]);
  *(s16x4*)(dst + (size_t)i * 4) = o;
}

// Wcomb[2048,512]: rows 0..511 = attn_W[n, 0:512]; rows 512..2047 = W_hh[n-512]
__global__ __launch_bounds__(256) void build_wcomb_k(const float* __restrict__ aW,
                                                     const float* __restrict__ whh,
                                                     unsigned short* __restrict__ dst) {
  int idx = (blockIdx.x * 256 + threadIdx.x) * 4;  // over 2048*512
  int n = idx >> 9, k = idx & 511;
  const float* src = (n < 512) ? (aW + (size_t)n * 1536 + k)
                               : (whh + (size_t)(n - 512) * 512 + k);
  f32x4 f = *(const f32x4*)src;
  s16x4 o;
#pragma unroll
  for (int j = 0; j < 4; ++j) o[j] = (short)f2bf(f[j]);
  *(s16x4*)(dst + idx) = o;
}

// Wenc[512,1024] = attn_W[:, 512:1536]
__global__ __launch_bounds__(256) void build_wenc_k(const float* __restrict__ aW,
                                                    unsigned short* __restrict__ dst) {
  int idx = (blockIdx.x * 256 + threadIdx.x) * 4;  // over 512*1024
  int n = idx >> 10, k = idx & 1023;
  f32x4 f = *(const f32x4*)(aW + (size_t)n * 1536 + 512 + k);
  s16x4 o;
#pragma unroll
  for (int j = 0; j < 4; ++j) o[j] = (short)f2bf(f[j]);
  *(s16x4*)(dst + idx) = o;
}

extern "C" void kernel_launch(void* const* d_in, const int* in_sizes, int n_in,
                              void* d_out, int out_size, void* d_ws, size_t ws_size,
                              hipStream_t stream) {
  const int* trg = (const int*)d_in[0];
  const int* srt = (const int*)d_in[1];
  const float* enc = (const float*)d_in[2];
  const float* hidden = (const float*)d_in[3];
  const float* embed = (const float*)d_in[4];
  const float* attn_W = (const float*)d_in[5];
  const float* attn_b = (const float*)d_in[6];
  const float* vv = (const float*)d_in[7];
  const float* W_ih = (const float*)d_in[8];
  const float* W_hh = (const float*)d_in[9];
  const float* b_ih = (const float*)d_in[10];
  const float* b_hh = (const float*)d_in[11];
  const float* out_W = (const float*)d_in[12];
  const float* out_b = (const float*)d_in[13];
  float* out = (float*)d_out;

  char* ws = (char*)d_ws;
  size_t off = 0;
  auto alloc = [&](size_t bytes) {
    size_t o = off;
    off += (bytes + 255) & ~(size_t)255;
    return o;
  };

  const size_t outW_bytes = (size_t)V_ * 2048 * 2;  // 131,072,000
  const size_t small_bytes = 4718592 + 2097152 + 1048576 + 16777216 + 524288 +
                             393216 + 393216 + 524288 + 131072 + 131072 + 4096;
  bool bf16W = (ws_size >= outW_bytes + small_bytes);

  unsigned short* outW_bf = nullptr;
  if (bf16W) outW_bf = (unsigned short*)(ws + alloc(outW_bytes));
  unsigned short* Wih_bf = (unsigned short*)(ws + alloc((size_t)1536 * 1536 * 2));
  unsigned short* Wcomb = (unsigned short*)(ws + alloc((size_t)2048 * 512 * 2));
  unsigned short* Wenc = (unsigned short*)(ws + alloc((size_t)512 * 1024 * 2));
  float* enc_proj = (float*)(ws + alloc((size_t)B_ * S_ * H_ * 4));
  float* hgh = (float*)(ws + alloc((size_t)B_ * 2048 * 4));
  float* xw = (float*)(ws + alloc((size_t)B_ * 1536 * 4));
  float* gi = (float*)(ws + alloc((size_t)B_ * 1536 * 4));
  float* out_feat = (float*)(ws + alloc((size_t)B_ * 2048 * 4));
  float* h0 = (float*)(ws + alloc((size_t)B_ * H_ * 4));
  float* h1 = (float*)(ws + alloc((size_t)B_ * H_ * 4));

  // outputs[0] = 0
  hipMemsetAsync(out, 0, (size_t)B_ * V_ * 4, stream);
  // h0 = hidden
  hipMemcpyAsync(h0, hidden, (size_t)B_ * H_ * 4, hipMemcpyDeviceToDevice, stream);

  // weight prep
  if (bf16W)
    cast_bf16_k<<<(V_ * 2048 / 4 + 255) / 256, 256, 0, stream>>>(out_W, outW_bf,
                                                                 V_ * 2048 / 4);
  cast_bf16_k<<<(1536 * 1536 / 4 + 255) / 256, 256, 0, stream>>>(W_ih, Wih_bf,
                                                                 1536 * 1536 / 4);
  build_wcomb_k<<<2048 * 512 / 4 / 256, 256, 0, stream>>>(attn_W, W_hh, Wcomb);
  build_wenc_k<<<512 * 1024 / 4 / 256, 256, 0, stream>>>(attn_W, Wenc);

  // enc_proj = enc_bt @ attn_W[:,512:]^T + attn_b   [B*S, 512]
  gemm_k<1, 0><<<dim3(H_ / 64, B_ * S_ / 64), 256, 0, stream>>>(
      enc, Wenc, attn_b, enc_proj, H_, 1024);

  for (int t = 0; t < T_ - 1; ++t) {
    float* hA = (t & 1) ? h1 : h0;
    float* hB = (t & 1) ? h0 : h1;
    // hgh = h @ [attn_Wh ; W_hh]^T   [64, 2048], K=512
    gemm_k<0, 0><<<dim3(2048 / 64, 1), 256, 0, stream>>>(hA, Wcomb, nullptr, hgh,
                                                         2048, 512);
    attn_k<<<B_, 256, 0, stream>>>(hgh, enc_proj, enc, vv, srt, trg, embed, t, xw,
                                   out_feat);
    // gi = [x, weighted] @ W_ih^T   [64, 1536], K=1536
    gemm_k<0, 0><<<dim3(1536 / 64, 1), 256, 0, stream>>>(xw, Wih_bf, nullptr, gi,
                                                         1536, 1536);
    gru_k<<<B_ * H_ / 256, 256, 0, stream>>>(gi, hgh, b_ih, b_hh, hA, hB, out_feat);
    // logits = out_feat @ out_W^T + out_b -> out[t+1]
    float* Ct = out + (size_t)(t + 1) * ((size_t)B_ * V_);
    if (bf16W)
      gemm_k<0, 0><<<dim3(V_ / 64, 1), 256, 0, stream>>>(out_feat, outW_bf, out_b,
                                                         Ct, V_, 2048);
    else
      gemm_k<0, 1><<<dim3(V_ / 64, 1), 256, 0, stream>>>(out_feat, out_W, out_b, Ct,
                                                         V_, 2048);
  }
}

// Round 2
// 3445.773 us; speedup vs baseline: 1.3606x; 1.3606x over previous
//
#include <hip/hip_runtime.h>

typedef __attribute__((ext_vector_type(4))) float f32x4;
typedef __attribute__((ext_vector_type(2))) float f32x2;
typedef __attribute__((ext_vector_type(8))) short s16x8;
typedef __attribute__((ext_vector_type(4))) short s16x4;
typedef __attribute__((ext_vector_type(2))) short s16x2;

#define B_ 64
#define S_ 128
#define T_ 32
#define H_ 512
#define V_ 32000

__device__ __forceinline__ unsigned short f2bf(float f) {
  union { float f; unsigned u; } x; x.f = f;
  unsigned r = x.u + 0x7FFFu + ((x.u >> 16) & 1u);
  return (unsigned short)(r >> 16);
}

__device__ __forceinline__ float fast_tanh(float x) {
  float e = __expf(2.0f * x);
  return 1.0f - 2.0f / (e + 1.0f);
}
__device__ __forceinline__ float fast_sig(float x) {
  return 1.0f / (1.0f + __expf(-x));
}

__device__ __forceinline__ void gload16(const void* g, void* l) {
  __builtin_amdgcn_global_load_lds(
      (const __attribute__((address_space(1))) void*)g,
      (__attribute__((address_space(3))) void*)l, 16, 0, 0);
}

// ---------------------------------------------------------------------------
// Small GEMM: C[M,N] = A[M,K] @ W[N,K]^T (+bias); 64x64 tile per block.
// A f32 (cast to bf16 in staging); W bf16 (WF32=1 -> f32 cast on the fly).
// ENC=1: A rows m=b*S+s map to encoder_out[s][b][:].
// ---------------------------------------------------------------------------
template <int ENC, int WF32>
__global__ __launch_bounds__(256) void gemm_k(
    const float* __restrict__ A, const void* __restrict__ Wv,
    const float* __restrict__ bias, float* __restrict__ C, int N, int K) {
  __shared__ unsigned short As[64 * 32];
  __shared__ unsigned short Bs[64 * 32];
  const int t = threadIdx.x;
  const int wave = t >> 6, lane = t & 63;
  const int n0 = blockIdx.x * 64;
  const int m0 = blockIdx.y * 64;
  const int row = t >> 2, part = t & 3;

  const float* arow;
  if (ENC) {
    int m = m0 + row;
    arow = A + ((size_t)(m & (S_ - 1)) * B_ + (m >> 7)) * (2 * H_);
  } else {
    arow = A + (size_t)(m0 + row) * K;
  }
  const char* wrow = (const char*)Wv + (size_t)(n0 + row) * K * (WF32 ? 4 : 2);

  f32x4 acc[4];
#pragma unroll
  for (int j = 0; j < 4; ++j) acc[j] = (f32x4){0.f, 0.f, 0.f, 0.f};

  const unsigned stg_off = (unsigned)(row * 64 + ((part ^ (row & 3)) << 4));
  const int ar = wave * 16 + (lane & 15);
  const unsigned a_off = (unsigned)(ar * 64 + (((lane >> 4) ^ (ar & 3)) << 4));

  for (int kk = 0; kk < K; kk += 32) {
    {
      const float* p = arow + kk + part * 8;
      f32x4 f0 = *(const f32x4*)p;
      f32x4 f1 = *(const f32x4*)(p + 4);
      s16x8 vb;
#pragma unroll
      for (int j = 0; j < 4; ++j) {
        vb[j] = (short)f2bf(f0[j]);
        vb[4 + j] = (short)f2bf(f1[j]);
      }
      *(s16x8*)((char*)As + stg_off) = vb;
    }
    {
      if (WF32) {
        const float* p = (const float*)wrow + kk + part * 8;
        f32x4 f0 = *(const f32x4*)p;
        f32x4 f1 = *(const f32x4*)(p + 4);
        s16x8 vb;
#pragma unroll
        for (int j = 0; j < 4; ++j) {
          vb[j] = (short)f2bf(f0[j]);
          vb[4 + j] = (short)f2bf(f1[j]);
        }
        *(s16x8*)((char*)Bs + stg_off) = vb;
      } else {
        const unsigned short* p = (const unsigned short*)wrow + kk + part * 8;
        *(s16x8*)((char*)Bs + stg_off) = *(const s16x8*)p;
      }
    }
    __syncthreads();
    s16x8 afrag = *(const s16x8*)((const char*)As + a_off);
#pragma unroll
    for (int j = 0; j < 4; ++j) {
      int cn = j * 16 + (lane & 15);
      s16x8 bfrag =
          *(const s16x8*)((const char*)Bs + cn * 64 + (((lane >> 4) ^ (cn & 3)) << 4));
      acc[j] = __builtin_amdgcn_mfma_f32_16x16x32_bf16(afrag, bfrag, acc[j], 0, 0, 0);
    }
    __syncthreads();
  }

#pragma unroll
  for (int j = 0; j < 4; ++j) {
    int col = n0 + j * 16 + (lane & 15);
    float bv = bias ? bias[col] : 0.0f;
#pragma unroll
    for (int i = 0; i < 4; ++i) {
      int r = m0 + wave * 16 + ((lane >> 4) << 2) + i;
      C[(size_t)r * N + col] = acc[j][i] + bv;
    }
  }
}

// ---------------------------------------------------------------------------
// Big GEMM (m97-style): C[Mv,N] = A[M,K]bf16 @ W[N,K]bf16^T + bias
// 128x128 tile, BK=32, 4 waves (2x2 of 64x64), global_load_lds width 16.
// M padded to 128 multiple; stores guarded by r < Mv. N%128==0, K%32==0.
// ---------------------------------------------------------------------------
__global__ __launch_bounds__(256) void big_gemm_k(
    const unsigned short* __restrict__ A, const unsigned short* __restrict__ W,
    const float* __restrict__ bias, float* __restrict__ C, int Mv, int N, int K) {
  __shared__ unsigned short As[128 * 32];
  __shared__ unsigned short Bs[128 * 32];
  const int t = threadIdx.x;
  const int wave = t >> 6, lane = t & 63;
  const int m0 = blockIdx.y * 128, n0 = blockIdx.x * 128;
  const int wm = (wave & 1) * 64, wn = (wave >> 1) * 64;

  f32x4 acc[4][4];
#pragma unroll
  for (int i = 0; i < 4; ++i)
#pragma unroll
    for (int j = 0; j < 4; ++j) acc[i][j] = (f32x4){0.f, 0.f, 0.f, 0.f};

  const size_t a_g0 = (size_t)(m0 + wave * 32 + (lane >> 2)) * K + (lane & 3) * 8;
  const size_t b_g0 = (size_t)(n0 + wave * 32 + (lane >> 2)) * K + (lane & 3) * 8;
  unsigned short* As_w = As + wave * 1024;
  unsigned short* Bs_w = Bs + wave * 1024;

  for (int kk = 0; kk < K; kk += 32) {
    gload16(A + a_g0 + kk, As_w);
    gload16(A + a_g0 + (size_t)16 * K + kk, As_w + 512);
    gload16(W + b_g0 + kk, Bs_w);
    gload16(W + b_g0 + (size_t)16 * K + kk, Bs_w + 512);
    __syncthreads();
    s16x8 af[4], bfr[4];
#pragma unroll
    for (int f = 0; f < 4; ++f) {
      af[f] = *(const s16x8*)(As + (wm + f * 16 + (lane & 15)) * 32 + (lane >> 4) * 8);
      bfr[f] = *(const s16x8*)(Bs + (wn + f * 16 + (lane & 15)) * 32 + (lane >> 4) * 8);
    }
#pragma unroll
    for (int fm = 0; fm < 4; ++fm)
#pragma unroll
      for (int fn = 0; fn < 4; ++fn)
        acc[fm][fn] =
            __builtin_amdgcn_mfma_f32_16x16x32_bf16(af[fm], bfr[fn], acc[fm][fn], 0, 0, 0);
    __syncthreads();
  }

#pragma unroll
  for (int fn = 0; fn < 4; ++fn) {
    int col = n0 + wn + fn * 16 + (lane & 15);
    float bv = bias[col];
#pragma unroll
    for (int fm = 0; fm < 4; ++fm) {
      int rb = m0 + wm + fm * 16 + ((lane >> 4) << 2);
#pragma unroll
      for (int i = 0; i < 4; ++i) {
        int r = rb + i;
        if (r < Mv) C[(size_t)r * N + col] = acc[fm][fn][i] + bv;
      }
    }
  }
}

// ---------------------------------------------------------------------------
// Attention per step; one block per batch b. Writes xw (f32, for gi GEMM) and
// (fast path) bf16 weighted/x into A_bf row step*64+b, or (fallback) out_feat.
// ---------------------------------------------------------------------------
__global__ __launch_bounds__(256) void attn_k(
    const float* __restrict__ hgh, const float* __restrict__ enc_proj,
    const float* __restrict__ enc, const float* __restrict__ v,
    const int* __restrict__ src_tok, const int* __restrict__ trg_tok,
    const float* __restrict__ embed, int step, float* __restrict__ xw,
    float* __restrict__ out_feat, unsigned short* __restrict__ Abf) {
  const int b = blockIdx.x;
  const int t = threadIdx.x, wave = t >> 6, lane = t & 63;
  __shared__ float sc[S_];

  const float* hp = hgh + (size_t)b * 2048;
  float vh[8], hh[8];
  {
    f32x4 v0 = *(const f32x4*)(v + lane * 8);
    f32x4 v1 = *(const f32x4*)(v + lane * 8 + 4);
    f32x4 h0 = *(const f32x4*)(hp + lane * 8);
    f32x4 h1 = *(const f32x4*)(hp + lane * 8 + 4);
#pragma unroll
    for (int j = 0; j < 4; ++j) {
      vh[j] = v0[j]; vh[4 + j] = v1[j];
      hh[j] = h0[j]; hh[4 + j] = h1[j];
    }
  }
  for (int s = wave * 32; s < wave * 32 + 32; ++s) {
    const float* ep = enc_proj + ((size_t)b * S_ + s) * H_ + lane * 8;
    f32x4 e0 = *(const f32x4*)ep;
    f32x4 e1 = *(const f32x4*)(ep + 4);
    float p = 0.f;
#pragma unroll
    for (int j = 0; j < 4; ++j) p += vh[j] * fast_tanh(hh[j] + e0[j]);
#pragma unroll
    for (int j = 0; j < 4; ++j) p += vh[4 + j] * fast_tanh(hh[4 + j] + e1[j]);
    for (int m = 32; m; m >>= 1) p += __shfl_xor(p, m);
    if (lane == 0)
      sc[s] = (src_tok[b * S_ + s] != 0) ? p : -__builtin_inff();
  }
  __syncthreads();
  if (wave == 0) {
    float a0 = sc[lane], a1 = sc[lane + 64];
    float mx = fmaxf(a0, a1);
    for (int m = 32; m; m >>= 1) mx = fmaxf(mx, __shfl_xor(mx, m));
    float e0 = __expf(a0 - mx), e1 = __expf(a1 - mx);
    float ssum = e0 + e1;
    for (int m = 32; m; m >>= 1) ssum += __shfl_xor(ssum, m);
    float inv = 1.0f / ssum;
    sc[lane] = e0 * inv;
    sc[lane + 64] = e1 * inv;
  }
  __syncthreads();
  const size_t arow = (size_t)(step * 64 + b) * 2048;
  {
    const int d0 = t * 4;
    f32x4 acc = {0.f, 0.f, 0.f, 0.f};
    for (int s = 0; s < S_; ++s) {
      f32x4 e = *(const f32x4*)(enc + ((size_t)s * B_ + b) * (2 * H_) + d0);
      float a = sc[s];
#pragma unroll
      for (int j = 0; j < 4; ++j) acc[j] += a * e[j];
    }
    *(f32x4*)(xw + (size_t)b * 1536 + 512 + d0) = acc;
    if (out_feat) *(f32x4*)(out_feat + (size_t)b * 2048 + 512 + d0) = acc;
    if (Abf) {
      s16x4 o;
#pragma unroll
      for (int j = 0; j < 4; ++j) o[j] = (short)f2bf(acc[j]);
      *(s16x4*)(Abf + arow + 512 + d0) = o;
    }
  }
  {
    int tok = trg_tok[b * T_ + step];
    const int d0 = t * 2;
    f32x2 xv = {0.f, 0.f};
    if (tok != 0) xv = *(const f32x2*)(embed + (size_t)tok * H_ + d0);
    *(f32x2*)(xw + (size_t)b * 1536 + d0) = xv;
    if (out_feat) *(f32x2*)(out_feat + (size_t)b * 2048 + 1536 + d0) = xv;
    if (Abf) {
      s16x2 o;
      o[0] = (short)f2bf(xv[0]);
      o[1] = (short)f2bf(xv[1]);
      *(s16x2*)(Abf + arow + 1536 + d0) = o;
    }
  }
}

// ---------------------------------------------------------------------------
// GRU elementwise
// ---------------------------------------------------------------------------
__global__ __launch_bounds__(256) void gru_k(
    const float* __restrict__ gi, const float* __restrict__ hgh,
    const float* __restrict__ b_ih, const float* __restrict__ b_hh,
    const float* __restrict__ h_in, float* __restrict__ h_out,
    float* __restrict__ out_feat, unsigned short* __restrict__ Abf, int step) {
  int i = blockIdx.x * 256 + threadIdx.x;
  int b = i >> 9, d = i & 511;
  const float* gib = gi + (size_t)b * 1536;
  const float* gh = hgh + (size_t)b * 2048 + 512;
  float ir = gib[d] + b_ih[d];
  float iz = gib[512 + d] + b_ih[512 + d];
  float in_ = gib[1024 + d] + b_ih[1024 + d];
  float hr = gh[d] + b_hh[d];
  float hz = gh[512 + d] + b_hh[512 + d];
  float hn = gh[1024 + d] + b_hh[1024 + d];
  float r = fast_sig(ir + hr);
  float z = fast_sig(iz + hz);
  float n = fast_tanh(in_ + r * hn);
  float h = (1.0f - z) * n + z * h_in[(size_t)b * 512 + d];
  h_out[(size_t)b * 512 + d] = h;
  if (out_feat) out_feat[(size_t)b * 2048 + d] = h;
  if (Abf) Abf[(size_t)(step * 64 + b) * 2048 + d] = f2bf(h);
}

// ---------------------------------------------------------------------------
// Prep kernels
// ---------------------------------------------------------------------------
__global__ __launch_bounds__(256) void cast_bf16_k(const float* __restrict__ src,
                                                   unsigned short* __restrict__ dst,
                                                   int n4) {
  int i = blockIdx.x * 256 + threadIdx.x;
  if (i >= n4) return;
  f32x4 f = *(const f32x4*)(src + (size_t)i * 4);
  s16x4 o;
#pragma unroll
  for (int j = 0; j < 4; ++j) o[j] = (short)f2bf(f[j]);
  *(s16x4*)(dst + (size_t)i * 4) = o;
}

// enc_bf[b*S+s][0:1024] = bf16(encoder_out[s][b][:])
__global__ __launch_bounds__(256) void enc_cast_k(const float* __restrict__ enc,
                                                  unsigned short* __restrict__ dst) {
  int i = blockIdx.x * 256 + threadIdx.x;  // over 8192*1024/4
  int n = i * 4;
  int row = n >> 10, d = n & 1023;
  int s = row & (S_ - 1), b = row >> 7;
  f32x4 f = *(const f32x4*)(enc + ((size_t)s * B_ + b) * 1024 + d);
  s16x4 o;
#pragma unroll
  for (int j = 0; j < 4; ++j) o[j] = (short)f2bf(f[j]);
  *(s16x4*)(dst + (size_t)row * 1024 + d) = o;
}

// Wcomb[2048,512]: rows 0..511 = attn_W[n, 0:512]; rows 512..2047 = W_hh[n-512]
__global__ __launch_bounds__(256) void build_wcomb_k(const float* __restrict__ aW,
                                                     const float* __restrict__ whh,
                                                     unsigned short* __restrict__ dst) {
  int idx = (blockIdx.x * 256 + threadIdx.x) * 4;
  int n = idx >> 9, k = idx & 511;
  const float* src = (n < 512) ? (aW + (size_t)n * 1536 + k)
                               : (whh + (size_t)(n - 512) * 512 + k);
  f32x4 f = *(const f32x4*)src;
  s16x4 o;
#pragma unroll
  for (int j = 0; j < 4; ++j) o[j] = (short)f2bf(f[j]);
  *(s16x4*)(dst + idx) = o;
}

// Wenc[512,1024] = attn_W[:, 512:1536]
__global__ __launch_bounds__(256) void build_wenc_k(const float* __restrict__ aW,
                                                    unsigned short* __restrict__ dst) {
  int idx = (blockIdx.x * 256 + threadIdx.x) * 4;
  int n = idx >> 10, k = idx & 1023;
  f32x4 f = *(const f32x4*)(aW + (size_t)n * 1536 + 512 + k);
  s16x4 o;
#pragma unroll
  for (int j = 0; j < 4; ++j) o[j] = (short)f2bf(f[j]);
  *(s16x4*)(dst + idx) = o;
}

extern "C" void kernel_launch(void* const* d_in, const int* in_sizes, int n_in,
                              void* d_out, int out_size, void* d_ws, size_t ws_size,
                              hipStream_t stream) {
  const int* trg = (const int*)d_in[0];
  const int* srt = (const int*)d_in[1];
  const float* enc = (const float*)d_in[2];
  const float* hidden = (const float*)d_in[3];
  const float* embed = (const float*)d_in[4];
  const float* attn_W = (const float*)d_in[5];
  const float* attn_b = (const float*)d_in[6];
  const float* vv = (const float*)d_in[7];
  const float* W_ih = (const float*)d_in[8];
  const float* W_hh = (const float*)d_in[9];
  const float* b_ih = (const float*)d_in[10];
  const float* b_hh = (const float*)d_in[11];
  const float* out_W = (const float*)d_in[12];
  const float* out_b = (const float*)d_in[13];
  float* out = (float*)d_out;

  char* ws = (char*)d_ws;
  size_t off = 0;
  auto alloc = [&](size_t bytes) {
    size_t o = off;
    off += (bytes + 255) & ~(size_t)255;
    return o;
  };

  const size_t outW_bytes = (size_t)V_ * 2048 * 2;              // 131 MB
  const size_t abf_bytes = (size_t)2048 * 2048 * 2;             // 8.4 MB
  const size_t encbf_bytes = (size_t)B_ * S_ * 1024 * 2;        // 16.8 MB
  const size_t small_bytes = (size_t)48 * 1024 * 1024;          // rest, generous
  bool fast = (ws_size >= outW_bytes + abf_bytes + encbf_bytes + small_bytes);
  bool bf16W = fast || (ws_size >= outW_bytes + small_bytes);

  unsigned short* outW_bf = nullptr;
  if (bf16W) outW_bf = (unsigned short*)(ws + alloc(outW_bytes));
  unsigned short* Abf = nullptr;
  unsigned short* enc_bf = nullptr;
  if (fast) {
    Abf = (unsigned short*)(ws + alloc(abf_bytes));
    enc_bf = (unsigned short*)(ws + alloc(encbf_bytes));
  }
  unsigned short* Wih_bf = (unsigned short*)(ws + alloc((size_t)1536 * 1536 * 2));
  unsigned short* Wcomb = (unsigned short*)(ws + alloc((size_t)2048 * 512 * 2));
  unsigned short* Wenc = (unsigned short*)(ws + alloc((size_t)512 * 1024 * 2));
  float* enc_proj = (float*)(ws + alloc((size_t)B_ * S_ * H_ * 4));
  float* hgh = (float*)(ws + alloc((size_t)B_ * 2048 * 4));
  float* xw = (float*)(ws + alloc((size_t)B_ * 1536 * 4));
  float* gi = (float*)(ws + alloc((size_t)B_ * 1536 * 4));
  float* out_feat = (float*)(ws + alloc((size_t)B_ * 2048 * 4));
  float* h0 = (float*)(ws + alloc((size_t)B_ * H_ * 4));
  float* h1 = (float*)(ws + alloc((size_t)B_ * H_ * 4));

  // outputs[0] = 0
  hipMemsetAsync(out, 0, (size_t)B_ * V_ * 4, stream);
  hipMemcpyAsync(h0, hidden, (size_t)B_ * H_ * 4, hipMemcpyDeviceToDevice, stream);

  // weight prep
  if (bf16W)
    cast_bf16_k<<<(V_ * 2048 / 4 + 255) / 256, 256, 0, stream>>>(out_W, outW_bf,
                                                                 V_ * 2048 / 4);
  cast_bf16_k<<<(1536 * 1536 / 4 + 255) / 256, 256, 0, stream>>>(W_ih, Wih_bf,
                                                                 1536 * 1536 / 4);
  build_wcomb_k<<<2048 * 512 / 4 / 256, 256, 0, stream>>>(attn_W, W_hh, Wcomb);
  build_wenc_k<<<512 * 1024 / 4 / 256, 256, 0, stream>>>(attn_W, Wenc);

  // enc_proj = enc_bt @ attn_W[:,512:]^T + attn_b   [B*S, 512]
  if (fast) {
    enc_cast_k<<<B_ * S_ * 1024 / 4 / 256, 256, 0, stream>>>(enc, enc_bf);
    big_gemm_k<<<dim3(512 / 128, B_ * S_ / 128), 256, 0, stream>>>(
        enc_bf, Wenc, attn_b, enc_proj, B_ * S_, H_, 1024);
  } else {
    gemm_k<1, 0><<<dim3(H_ / 64, B_ * S_ / 64), 256, 0, stream>>>(
        enc, Wenc, attn_b, enc_proj, H_, 1024);
  }

  float* of = fast ? nullptr : out_feat;
  for (int t = 0; t < T_ - 1; ++t) {
    float* hA = (t & 1) ? h1 : h0;
    float* hB = (t & 1) ? h0 : h1;
    gemm_k<0, 0><<<dim3(2048 / 64, 1), 256, 0, stream>>>(hA, Wcomb, nullptr, hgh,
                                                         2048, 512);
    attn_k<<<B_, 256, 0, stream>>>(hgh, enc_proj, enc, vv, srt, trg, embed, t, xw,
                                   of, Abf);
    gemm_k<0, 0><<<dim3(1536 / 64, 1), 256, 0, stream>>>(xw, Wih_bf, nullptr, gi,
                                                         1536, 1536);
    gru_k<<<B_ * H_ / 256, 256, 0, stream>>>(gi, hgh, b_ih, b_hh, hA, hB, of, Abf,
                                             t);
    if (!fast) {
      float* Ct = out + (size_t)(t + 1) * ((size_t)B_ * V_);
      if (bf16W)
        gemm_k<0, 0><<<dim3(V_ / 64, 1), 256, 0, stream>>>(out_feat, outW_bf, out_b,
                                                           Ct, V_, 2048);
      else
        gemm_k<0, 1><<<dim3(V_ / 64, 1), 256, 0, stream>>>(out_feat, out_W, out_b,
                                                           Ct, V_, 2048);
    }
  }

  if (fast) {
    // logits for all steps: [1984, 32000] = Abf @ outW^T + out_b
    big_gemm_k<<<dim3(V_ / 128, 2048 / 128), 256, 0, stream>>>(
        Abf, outW_bf, out_b, out + (size_t)B_ * V_, (T_ - 1) * B_, V_, 2048);
  }
}

// Round 3
// 2266.126 us; speedup vs baseline: 2.0688x; 1.5206x over previous
//
#include <hip/hip_runtime.h>

typedef __attribute__((ext_vector_type(4))) float f32x4;
typedef __attribute__((ext_vector_type(2))) float f32x2;
typedef __attribute__((ext_vector_type(8))) short s16x8;
typedef __attribute__((ext_vector_type(4))) short s16x4;

#define B_ 64
#define S_ 128
#define T_ 32
#define H_ 512
#define V_ 32000

__device__ __forceinline__ unsigned short f2bf(float f) {
  union { float f; unsigned u; } x; x.f = f;
  unsigned r = x.u + 0x7FFFu + ((x.u >> 16) & 1u);
  return (unsigned short)(r >> 16);
}
__device__ __forceinline__ float bf2f(unsigned short u) {
  union { unsigned u; float f; } x; x.u = ((unsigned)u) << 16; return x.f;
}
__device__ __forceinline__ float fast_tanh(float x) {
  float e = __expf(2.0f * x);
  return 1.0f - 2.0f / (e + 1.0f);
}
__device__ __forceinline__ float fast_sig(float x) {
  return 1.0f / (1.0f + __expf(-x));
}
__device__ __forceinline__ void gload16(const void* g, void* l) {
  __builtin_amdgcn_global_load_lds(
      (const __attribute__((address_space(1))) void*)g,
      (__attribute__((address_space(3))) void*)l, 16, 0, 0);
}

// Grid barrier: monotone counter, agent-scope atomics. cnt memset to 0 per call.
__device__ __forceinline__ void gbar(unsigned* cnt, unsigned target) {
  __syncthreads();
  if (threadIdx.x == 0) {
    __hip_atomic_fetch_add(cnt, 1u, __ATOMIC_ACQ_REL, __HIP_MEMORY_SCOPE_AGENT);
    while (__hip_atomic_fetch_add(cnt, 0u, __ATOMIC_ACQUIRE,
                                  __HIP_MEMORY_SCOPE_AGENT) < target)
      __builtin_amdgcn_s_sleep(1);
  }
  __syncthreads();
}

// ---------------------------------------------------------------------------
// Big GEMM: C[Mv,N] = A[.,K]bf16(lda) @ W[N,K]bf16^T + bias
// 128x128 tile, BK=32, global_load_lds w=16, XOR-swizzled LDS (both sides).
// grid: x = M-tiles (fastest -> XCD = m%8, A L2-resident), y = N-tiles.
// ---------------------------------------------------------------------------
template <int OUTBF>
__global__ __launch_bounds__(256) void big_gemm_k(
    const unsigned short* __restrict__ A, int lda,
    const unsigned short* __restrict__ W, const float* __restrict__ bias,
    void* __restrict__ Cv, int Mv, int N, int K) {
  __shared__ unsigned short As[128 * 32];
  __shared__ unsigned short Bs[128 * 32];
  const int t = threadIdx.x;
  const int wave = t >> 6, lane = t & 63;
  const int m0 = blockIdx.x * 128, n0 = blockIdx.y * 128;
  const int wm = (wave & 1) * 64, wn = (wave >> 1) * 64;
  const int fr = lane & 15, fq = lane >> 4;

  f32x4 acc[4][4];
#pragma unroll
  for (int i = 0; i < 4; ++i)
#pragma unroll
    for (int j = 0; j < 4; ++j) acc[i][j] = (f32x4){0.f, 0.f, 0.f, 0.f};

  // pre-swizzled global source chunk (rule #21: linear LDS dest + swz source)
  const int g = (((lane & 3) ^ ((lane >> 3) & 3))) * 8;
  const size_t a_g0 = (size_t)(m0 + wave * 32 + (lane >> 2)) * lda + g;
  const size_t b_g0 = (size_t)(n0 + wave * 32 + (lane >> 2)) * K + g;
  unsigned short* As_w = As + wave * 1024;
  unsigned short* Bs_w = Bs + wave * 1024;
  const int sl = (fq ^ ((fr >> 1) & 3)) * 8;  // swizzled read slot

  for (int kk = 0; kk < K; kk += 32) {
    gload16(A + a_g0 + kk, As_w);
    gload16(A + a_g0 + (size_t)16 * lda + kk, As_w + 512);
    gload16(W + b_g0 + kk, Bs_w);
    gload16(W + b_g0 + (size_t)16 * K + kk, Bs_w + 512);
    __syncthreads();
    s16x8 af[4], bfr[4];
#pragma unroll
    for (int f = 0; f < 4; ++f) {
      af[f] = *(const s16x8*)(As + (wm + f * 16 + fr) * 32 + sl);
      bfr[f] = *(const s16x8*)(Bs + (wn + f * 16 + fr) * 32 + sl);
    }
#pragma unroll
    for (int fm = 0; fm < 4; ++fm)
#pragma unroll
      for (int fn = 0; fn < 4; ++fn)
        acc[fm][fn] = __builtin_amdgcn_mfma_f32_16x16x32_bf16(af[fm], bfr[fn],
                                                              acc[fm][fn], 0, 0, 0);
    __syncthreads();
  }

#pragma unroll
  for (int fn = 0; fn < 4; ++fn) {
    int col = n0 + wn + fn * 16 + fr;
    float bv = bias[col];
#pragma unroll
    for (int fm = 0; fm < 4; ++fm) {
      int rb = m0 + wm + fm * 16 + fq * 4;
#pragma unroll
      for (int i = 0; i < 4; ++i) {
        int r = rb + i;
        if (r < Mv) {
          if (OUTBF)
            ((unsigned short*)Cv)[(size_t)r * N + col] = f2bf(acc[fm][fn][i] + bv);
          else
            ((float*)Cv)[(size_t)r * N + col] = acc[fm][fn][i] + bv;
        }
      }
    }
  }
}

// ---------------------------------------------------------------------------
// Mega-kernel: runs all 31 steps. 64 blocks x 512 threads.
// P1: hgh[64,2048] = hbf @ Wcomb^T (block j -> cols j*32..+31)
// P2: attention for b = j (energy/softmax/weighted -> Abf cols 512:1536)
// P3 (j<32): gi_w tile {d0,512+d0,1024+d0} x 64b + fused GRU -> h/hbf/Abf
// ---------------------------------------------------------------------------
__global__ __launch_bounds__(512) void loop_k(
    float* __restrict__ h, unsigned short* __restrict__ hbf,
    float* __restrict__ hgh, const unsigned short* __restrict__ Wcomb,
    const unsigned short* __restrict__ encp_bf,
    const unsigned short* __restrict__ enc_bf, const float* __restrict__ v,
    const int* __restrict__ src_tok, const unsigned short* __restrict__ Ww,
    const float* __restrict__ gi_x, const float* __restrict__ b_hh,
    unsigned short* __restrict__ Abf, unsigned* __restrict__ bar) {
  const int j = blockIdx.x;
  const int t = threadIdx.x;
  const int lane = t & 63, w = t >> 6;
  const int fr = lane & 15, fq = lane >> 4;
  const int ar = t >> 3, ak = (t & 7) * 8;  // stage coords (64 rows x 8 chunks)
  unsigned target = 0;

  __shared__ unsigned short Asm[64 * 72];
  __shared__ unsigned short Wsm[48 * 72];
  __shared__ float gsm[64 * 48];
  __shared__ float sc[132];

  const int p1_n0 = j * 32;
  const int rowt_p1 = w & 3, colt_p1 = w >> 2;

  for (int step = 0; step < 31; ++step) {
    // ---------------- P1 ----------------
    {
      s16x8 pa = *(const s16x8*)(hbf + ar * 512 + ak);
      s16x8 pw;
      if (t < 256) pw = *(const s16x8*)(Wcomb + (size_t)(p1_n0 + ar) * 512 + ak);
      *(s16x8*)(Asm + ar * 72 + ak) = pa;
      if (t < 256) *(s16x8*)(Wsm + ar * 72 + ak) = pw;
      __syncthreads();
      f32x4 acc = {0.f, 0.f, 0.f, 0.f};
      for (int it = 0; it < 8; ++it) {
        int kn = (it + 1) * 64;
        if (it < 7) {
          pa = *(const s16x8*)(hbf + ar * 512 + kn + ak);
          if (t < 256)
            pw = *(const s16x8*)(Wcomb + (size_t)(p1_n0 + ar) * 512 + kn + ak);
        }
        s16x8 a0 = *(const s16x8*)(Asm + (rowt_p1 * 16 + fr) * 72 + fq * 8);
        s16x8 a1 = *(const s16x8*)(Asm + (rowt_p1 * 16 + fr) * 72 + 32 + fq * 8);
        s16x8 b0 = *(const s16x8*)(Wsm + (colt_p1 * 16 + fr) * 72 + fq * 8);
        s16x8 b1 = *(const s16x8*)(Wsm + (colt_p1 * 16 + fr) * 72 + 32 + fq * 8);
        acc = __builtin_amdgcn_mfma_f32_16x16x32_bf16(a0, b0, acc, 0, 0, 0);
        acc = __builtin_amdgcn_mfma_f32_16x16x32_bf16(a1, b1, acc, 0, 0, 0);
        __syncthreads();
        if (it < 7) {
          *(s16x8*)(Asm + ar * 72 + ak) = pa;
          if (t < 256) *(s16x8*)(Wsm + ar * 72 + ak) = pw;
          __syncthreads();
        }
      }
      int col = p1_n0 + colt_p1 * 16 + fr;
#pragma unroll
      for (int i = 0; i < 4; ++i)
        hgh[(rowt_p1 * 16 + fq * 4 + i) * 2048 + col] = acc[i];
    }
    target += 64; gbar(bar, target);

    // ---------------- P2: attention for b = j ----------------
    {
      const int b = j;
      const float* hp = hgh + b * 2048;
      float vh[8], hh[8];
      {
        f32x4 v0 = *(const f32x4*)(v + lane * 8);
        f32x4 v1 = *(const f32x4*)(v + lane * 8 + 4);
        f32x4 h0 = *(const f32x4*)(hp + lane * 8);
        f32x4 h1 = *(const f32x4*)(hp + lane * 8 + 4);
#pragma unroll
        for (int q = 0; q < 4; ++q) {
          vh[q] = v0[q]; vh[4 + q] = v1[q];
          hh[q] = h0[q]; hh[4 + q] = h1[q];
        }
      }
      for (int s = w * 16; s < w * 16 + 16; ++s) {
        s16x8 e = *(const s16x8*)(encp_bf + (size_t)(b * 128 + s) * 512 + lane * 8);
        float p = 0.f;
#pragma unroll
        for (int q = 0; q < 8; ++q)
          p += vh[q] * fast_tanh(hh[q] + bf2f((unsigned short)e[q]));
        for (int m = 32; m; m >>= 1) p += __shfl_xor(p, m);
        if (lane == 0)
          sc[s] = (src_tok[b * 128 + s] != 0) ? p : -__builtin_inff();
      }
      __syncthreads();
      if (t < 64) {
        float a0 = sc[t], a1 = sc[t + 64];
        float mx = fmaxf(a0, a1);
        for (int m = 32; m; m >>= 1) mx = fmaxf(mx, __shfl_xor(mx, m));
        float e0 = __expf(a0 - mx), e1 = __expf(a1 - mx);
        float ssum = e0 + e1;
        for (int m = 32; m; m >>= 1) ssum += __shfl_xor(ssum, m);
        float inv = 1.0f / ssum;
        sc[t] = e0 * inv;
        sc[t + 64] = e1 * inv;
      }
      __syncthreads();
      const int d = t * 2;
      float w0 = 0.f, w1 = 0.f;
#pragma unroll 8
      for (int s = 0; s < 128; ++s) {
        float a = sc[s];
        unsigned u = *(const unsigned*)(enc_bf + (size_t)(b * 128 + s) * 1024 + d);
        union { unsigned u; float f; } lo, hi;
        lo.u = u << 16; hi.u = u & 0xffff0000u;
        w0 += a * lo.f; w1 += a * hi.f;
      }
      unsigned pk = ((unsigned)f2bf(w1) << 16) | (unsigned)f2bf(w0);
      *(unsigned*)(Abf + (size_t)(step * 64 + b) * 2048 + 512 + d) = pk;
    }
    target += 64; gbar(bar, target);

    // ---------------- P3 + GRU (blocks j < 32) ----------------
    if (j < 32) {
      const int d0 = j * 16;
      const int r0 = step * 64;
      const int rowt = (w < 4) ? w : (w - 4);
      const int wgate = ar >> 4, wdr = ar & 15;  // ar in 0..47 when t<384
      const unsigned short* wwrow =
          Ww + (size_t)(wgate * 512 + d0 + wdr) * 1024 + ak;
      s16x8 pa = *(const s16x8*)(Abf + (size_t)(r0 + ar) * 2048 + 512 + ak);
      s16x8 pw;
      if (t < 384) pw = *(const s16x8*)(wwrow);
      *(s16x8*)(Asm + ar * 72 + ak) = pa;
      if (t < 384) *(s16x8*)(Wsm + ar * 72 + ak) = pw;
      __syncthreads();
      f32x4 acc0 = {0.f, 0.f, 0.f, 0.f}, acc1 = {0.f, 0.f, 0.f, 0.f};
      for (int it = 0; it < 16; ++it) {
        int kn = (it + 1) * 64;
        if (it < 15) {
          pa = *(const s16x8*)(Abf + (size_t)(r0 + ar) * 2048 + 512 + kn + ak);
          if (t < 384) pw = *(const s16x8*)(wwrow + kn);
        }
        s16x8 a0 = *(const s16x8*)(Asm + (rowt * 16 + fr) * 72 + fq * 8);
        s16x8 a1 = *(const s16x8*)(Asm + (rowt * 16 + fr) * 72 + 32 + fq * 8);
        if (w < 4) {
          s16x8 b0 = *(const s16x8*)(Wsm + fr * 72 + fq * 8);
          s16x8 b1 = *(const s16x8*)(Wsm + fr * 72 + 32 + fq * 8);
          s16x8 c0 = *(const s16x8*)(Wsm + (32 + fr) * 72 + fq * 8);
          s16x8 c1 = *(const s16x8*)(Wsm + (32 + fr) * 72 + 32 + fq * 8);
          acc0 = __builtin_amdgcn_mfma_f32_16x16x32_bf16(a0, b0, acc0, 0, 0, 0);
          acc0 = __builtin_amdgcn_mfma_f32_16x16x32_bf16(a1, b1, acc0, 0, 0, 0);
          acc1 = __builtin_amdgcn_mfma_f32_16x16x32_bf16(a0, c0, acc1, 0, 0, 0);
          acc1 = __builtin_amdgcn_mfma_f32_16x16x32_bf16(a1, c1, acc1, 0, 0, 0);
        } else {
          s16x8 b0 = *(const s16x8*)(Wsm + (16 + fr) * 72 + fq * 8);
          s16x8 b1 = *(const s16x8*)(Wsm + (16 + fr) * 72 + 32 + fq * 8);
          acc0 = __builtin_amdgcn_mfma_f32_16x16x32_bf16(a0, b0, acc0, 0, 0, 0);
          acc0 = __builtin_amdgcn_mfma_f32_16x16x32_bf16(a1, b1, acc0, 0, 0, 0);
        }
        __syncthreads();
        if (it < 15) {
          *(s16x8*)(Asm + ar * 72 + ak) = pa;
          if (t < 384) *(s16x8*)(Wsm + ar * 72 + ak) = pw;
          __syncthreads();
        }
      }
      {
        const int colt0 = (w < 4) ? 0 : 1;
#pragma unroll
        for (int i = 0; i < 4; ++i) {
          int row = rowt * 16 + fq * 4 + i;
          gsm[row * 48 + colt0 * 16 + fr] =
              acc0[i] + gi_x[(size_t)(r0 + row) * 1536 + colt0 * 512 + d0 + fr];
        }
        if (w < 4) {
#pragma unroll
          for (int i = 0; i < 4; ++i) {
            int row = rowt * 16 + fq * 4 + i;
            gsm[row * 48 + 32 + fr] =
                acc1[i] + gi_x[(size_t)(r0 + row) * 1536 + 1024 + d0 + fr];
          }
        }
      }
      __syncthreads();
#pragma unroll
      for (int e = t * 2; e < t * 2 + 2; ++e) {
        int b = e >> 4, dd = e & 15, d = d0 + dd;
        float ir = gsm[b * 48 + dd];
        float iz = gsm[b * 48 + 16 + dd];
        float inn = gsm[b * 48 + 32 + dd];
        float hr = hgh[b * 2048 + 512 + d] + b_hh[d];
        float hz = hgh[b * 2048 + 1024 + d] + b_hh[512 + d];
        float hn = hgh[b * 2048 + 1536 + d] + b_hh[1024 + d];
        float r = fast_sig(ir + hr);
        float z = fast_sig(iz + hz);
        float n = fast_tanh(inn + r * hn);
        float hv = (1.0f - z) * n + z * h[b * 512 + d];
        h[b * 512 + d] = hv;
        unsigned short hb = f2bf(hv);
        hbf[b * 512 + d] = hb;
        Abf[(size_t)(r0 + b) * 2048 + d] = hb;
      }
    }
    if (step < 30) { target += 64; gbar(bar, target); }
  }
}

// ---------------------------------------------------------------------------
// Prep kernels
// ---------------------------------------------------------------------------
__global__ __launch_bounds__(256) void cast_bf16_k(const float* __restrict__ src,
                                                   unsigned short* __restrict__ dst,
                                                   int n4) {
  int i = blockIdx.x * 256 + threadIdx.x;
  if (i >= n4) return;
  f32x4 f = *(const f32x4*)(src + (size_t)i * 4);
  s16x4 o;
#pragma unroll
  for (int q = 0; q < 4; ++q) o[q] = (short)f2bf(f[q]);
  *(s16x4*)(dst + (size_t)i * 4) = o;
}

__global__ __launch_bounds__(256) void enc_cast_k(const float* __restrict__ enc,
                                                  unsigned short* __restrict__ dst) {
  int i = blockIdx.x * 256 + threadIdx.x;
  int n = i * 4;
  int row = n >> 10, d = n & 1023;
  int s = row & (S_ - 1), b = row >> 7;
  f32x4 f = *(const f32x4*)(enc + ((size_t)s * B_ + b) * 1024 + d);
  s16x4 o;
#pragma unroll
  for (int q = 0; q < 4; ++q) o[q] = (short)f2bf(f[q]);
  *(s16x4*)(dst + (size_t)row * 1024 + d) = o;
}

// Wcomb[2048,512]: rows 0..511 = attn_W[n,0:512]; rows 512..2047 = W_hh[n-512]
__global__ __launch_bounds__(256) void build_wcomb_k(const float* __restrict__ aW,
                                                     const float* __restrict__ whh,
                                                     unsigned short* __restrict__ dst) {
  int idx = (blockIdx.x * 256 + threadIdx.x) * 4;
  int n = idx >> 9, k = idx & 511;
  const float* src = (n < 512) ? (aW + (size_t)n * 1536 + k)
                               : (whh + (size_t)(n - 512) * 512 + k);
  f32x4 f = *(const f32x4*)src;
  s16x4 o;
#pragma unroll
  for (int q = 0; q < 4; ++q) o[q] = (short)f2bf(f[q]);
  *(s16x4*)(dst + idx) = o;
}

// Wenc[512,1024] = attn_W[:, 512:1536]
__global__ __launch_bounds__(256) void build_wenc_k(const float* __restrict__ aW,
                                                    unsigned short* __restrict__ dst) {
  int idx = (blockIdx.x * 256 + threadIdx.x) * 4;
  int n = idx >> 10, k = idx & 1023;
  f32x4 f = *(const f32x4*)(aW + (size_t)n * 1536 + 512 + k);
  s16x4 o;
#pragma unroll
  for (int q = 0; q < 4; ++q) o[q] = (short)f2bf(f[q]);
  *(s16x4*)(dst + idx) = o;
}

// Wx[1536,512] = W_ih[:,0:512]; Ww[1536,1024] = W_ih[:,512:1536]
__global__ __launch_bounds__(256) void build_wxw_k(const float* __restrict__ wih,
                                                   unsigned short* __restrict__ wx,
                                                   unsigned short* __restrict__ ww) {
  int flat = blockIdx.x * 256 + threadIdx.x;  // over 1536*384
  int n = flat / 384, c4 = (flat % 384) * 4;
  f32x4 f = *(const f32x4*)(wih + (size_t)n * 1536 + c4);
  s16x4 o;
#pragma unroll
  for (int q = 0; q < 4; ++q) o[q] = (short)f2bf(f[q]);
  if (c4 < 512)
    *(s16x4*)(wx + (size_t)n * 512 + c4) = o;
  else
    *(s16x4*)(ww + (size_t)n * 1024 + (c4 - 512)) = o;
}

__global__ __launch_bounds__(256) void hcast_k(const float* __restrict__ hidden,
                                               unsigned short* __restrict__ hbf) {
  int i = blockIdx.x * 256 + threadIdx.x;  // 16384 threads
  f32x2 f = *(const f32x2*)(hidden + (size_t)i * 2);
  unsigned pk = ((unsigned)f2bf(f[1]) << 16) | (unsigned)f2bf(f[0]);
  *(unsigned*)(hbf + (size_t)i * 2) = pk;
}

// Abf[row, 1536:2048] = bf16(embed[trg[b, t]]) for row = t*64+b  (PAD -> 0)
__global__ __launch_bounds__(256) void xgather_k(const int* __restrict__ trg,
                                                 const float* __restrict__ embed,
                                                 unsigned short* __restrict__ Abf) {
  int row = blockIdx.x;  // 0..1983
  int tt = row >> 6, b = row & 63;
  int tok = trg[b * T_ + tt];
  int d = threadIdx.x * 2;
  unsigned pk = 0;
  if (tok != 0) {
    f32x2 f = *(const f32x2*)(embed + (size_t)tok * H_ + d);
    pk = ((unsigned)f2bf(f[1]) << 16) | (unsigned)f2bf(f[0]);
  }
  *(unsigned*)(Abf + (size_t)row * 2048 + 1536 + d) = pk;
}

extern "C" void kernel_launch(void* const* d_in, const int* in_sizes, int n_in,
                              void* d_out, int out_size, void* d_ws, size_t ws_size,
                              hipStream_t stream) {
  const int* trg = (const int*)d_in[0];
  const int* srt = (const int*)d_in[1];
  const float* enc = (const float*)d_in[2];
  const float* hidden = (const float*)d_in[3];
  const float* embed = (const float*)d_in[4];
  const float* attn_W = (const float*)d_in[5];
  const float* attn_b = (const float*)d_in[6];
  const float* vv = (const float*)d_in[7];
  const float* W_ih = (const float*)d_in[8];
  const float* W_hh = (const float*)d_in[9];
  const float* b_ih = (const float*)d_in[10];
  const float* b_hh = (const float*)d_in[11];
  const float* out_W = (const float*)d_in[12];
  const float* out_b = (const float*)d_in[13];
  float* out = (float*)d_out;

  char* ws = (char*)d_ws;
  size_t off = 0;
  auto alloc = [&](size_t bytes) {
    size_t o = off;
    off += (bytes + 255) & ~(size_t)255;
    return ws + o;
  };

  unsigned short* outW_bf = (unsigned short*)alloc((size_t)V_ * 2048 * 2);  // 131MB
  unsigned short* Abf = (unsigned short*)alloc((size_t)2048 * 2048 * 2);    // 8.4MB
  unsigned short* enc_bf = (unsigned short*)alloc((size_t)B_ * S_ * 1024 * 2);
  unsigned short* encp_bf = (unsigned short*)alloc((size_t)B_ * S_ * 512 * 2);
  float* gi_x = (float*)alloc((size_t)1984 * 1536 * 4);
  unsigned short* Wcomb = (unsigned short*)alloc((size_t)2048 * 512 * 2);
  unsigned short* Wenc = (unsigned short*)alloc((size_t)512 * 1024 * 2);
  unsigned short* Wx = (unsigned short*)alloc((size_t)1536 * 512 * 2);
  unsigned short* Ww = (unsigned short*)alloc((size_t)1536 * 1024 * 2);
  float* hgh = (float*)alloc((size_t)B_ * 2048 * 4);
  float* h = (float*)alloc((size_t)B_ * H_ * 4);
  unsigned short* hbf = (unsigned short*)alloc((size_t)B_ * H_ * 2);
  unsigned* bar = (unsigned*)alloc(256);

  // outputs[0] = 0; barrier counter = 0; h = hidden
  hipMemsetAsync(out, 0, (size_t)B_ * V_ * 4, stream);
  hipMemsetAsync(bar, 0, 256, stream);
  hipMemcpyAsync(h, hidden, (size_t)B_ * H_ * 4, hipMemcpyDeviceToDevice, stream);

  // weight/input prep
  cast_bf16_k<<<(V_ * 2048 / 4 + 255) / 256, 256, 0, stream>>>(out_W, outW_bf,
                                                               V_ * 2048 / 4);
  build_wcomb_k<<<2048 * 512 / 4 / 256, 256, 0, stream>>>(attn_W, W_hh, Wcomb);
  build_wenc_k<<<512 * 1024 / 4 / 256, 256, 0, stream>>>(attn_W, Wenc);
  build_wxw_k<<<1536 * 384 / 256, 256, 0, stream>>>(W_ih, Wx, Ww);
  hcast_k<<<64, 256, 0, stream>>>(hidden, hbf);
  enc_cast_k<<<B_ * S_ * 1024 / 4 / 256, 256, 0, stream>>>(enc, enc_bf);
  xgather_k<<<1984, 256, 0, stream>>>(trg, embed, Abf);

  // enc_proj_bf[8192,512] = enc_bf @ Wenc^T + attn_b (bf16 out)
  big_gemm_k<1><<<dim3(64, 4), 256, 0, stream>>>(enc_bf, 1024, Wenc, attn_b,
                                                 encp_bf, B_ * S_, 512, 1024);
  // gi_x[1984,1536] = x @ Wx^T + b_ih (f32 out); A = Abf cols 1536:2048
  big_gemm_k<0><<<dim3(16, 12), 256, 0, stream>>>(Abf + 1536, 2048, Wx, b_ih,
                                                  gi_x, 1984, 1536, 512);

  // the 31-step recurrence, one launch
  loop_k<<<64, 512, 0, stream>>>(h, hbf, hgh, Wcomb, encp_bf, enc_bf, vv, srt, Ww,
                                 gi_x, b_hh, Abf, bar);

  // logits for all steps: out[1..31] = Abf @ outW^T + out_b
  big_gemm_k<0><<<dim3(16, 250), 256, 0, stream>>>(Abf, 2048, outW_bf, out_b,
                                                   out + (size_t)B_ * V_,
                                                   (T_ - 1) * B_, V_, 2048);
}